// Round 5
// baseline (115.887 us; speedup 1.0000x reference)
//
#include <hip/hip_runtime.h>

#define NROWS 8192
#define HALF_N 4096
#define DIM 512
#define INV_T 10.0f
#define NBLOCKS 1056        // sum_{rb=0..31} (64 - 2*rb) 256x128 tiles

typedef __attribute__((ext_vector_type(4))) float f32x4;
typedef __attribute__((ext_vector_type(2))) long long2v;

// async 16B global -> LDS (DMA). LDS dest is wave-uniform base + lane*16.
__device__ __forceinline__ void async16(const void* g, void* l) {
  __builtin_amdgcn_global_load_lds(
      (const __attribute__((address_space(1))) unsigned int*)g,
      (__attribute__((address_space(3))) unsigned int*)l, 16, 0, 0);
}

// Kernel 1: L2-normalize rows of [f1;f2] -> fp8 e4m3, written TWICE:
//  Fb: row-major, k-permuted within each 64B group (unit u -> pos
//      2*(u&3)+(u>>2)) — the B/LDS copy (R8-proven geometry).
//  Fa: fragment-major — panel p = row>>4 is 8 KB laid out as
//      [chunk c=0..31][row&15][16B], where chunk c holds k-units {c&3, (c&3)+4}
//      of k-group c>>2 (same pairing as Fb). A-fragment loads in the GEMM
//      become coalesced global b128 (quarter-wave = 256 B contiguous).
__global__ __launch_bounds__(256) void norm_cast_k(
    const float* __restrict__ f1, const float* __restrict__ f2,
    unsigned char* __restrict__ Fa, unsigned char* __restrict__ Fb,
    float* __restrict__ rowsum, float* __restrict__ out) {
  int wave = threadIdx.x >> 6;
  int lane = threadIdx.x & 63;
  int row = blockIdx.x * 4 + wave;
  const float* src = (row < HALF_N) ? (f1 + (size_t)row * DIM)
                                    : (f2 + (size_t)(row - HALF_N) * DIM);
  const float4* p = reinterpret_cast<const float4*>(src + lane * 8);
  float4 v0 = p[0];
  float4 v1 = p[1];
  float ss = v0.x*v0.x + v0.y*v0.y + v0.z*v0.z + v0.w*v0.w
           + v1.x*v1.x + v1.y*v1.y + v1.z*v1.z + v1.w*v1.w;
  #pragma unroll
  for (int off = 1; off < 64; off <<= 1) ss += __shfl_xor(ss, off);
  float scale = 1.0f / fmaxf(sqrtf(ss), 1e-12f);
  int lo = __builtin_amdgcn_cvt_pk_fp8_f32(v0.x * scale, v0.y * scale, 0, false);
  lo = __builtin_amdgcn_cvt_pk_fp8_f32(v0.z * scale, v0.w * scale, lo, true);
  int hi = __builtin_amdgcn_cvt_pk_fp8_f32(v1.x * scale, v1.y * scale, 0, false);
  hi = __builtin_amdgcn_cvt_pk_fp8_f32(v1.z * scale, v1.w * scale, hi, true);
  int2 val = make_int2(lo, hi);
  int u = lane & 7;                     // k-unit within 64B group
  int g = lane >> 3;                    // k-group (0..7)
  // Fb: row-major k-permuted
  int pos = 2 * (u & 3) + (u >> 2);
  *reinterpret_cast<int2*>(Fb + (size_t)row * DIM + g * 64 + pos * 8) = val;
  // Fa: fragment-major
  int chunk = g * 4 + (u & 3);          // global 16B chunk index (0..31)
  int slot = u >> 2;                    // which 8B half of the chunk
  *reinterpret_cast<int2*>(Fa + (size_t)(row >> 4) * 8192 + chunk * 256 +
                           (row & 15) * 16 + slot * 8) = val;
  if (lane == 0) rowsum[row] = 0.0f;
  if (blockIdx.x == 0 && threadIdx.x == 0) out[0] = 0.0f;
}

// Kernel 2: symmetric upper-triangle sim GEMM (fp8 e4m3 16x16x32, non-scaled;
// the MX-scaled builtin spills v8i32 operands via scratch on this ROCm —
// R1-R3: identical 84 VGPR + 290 MB scratch regardless of source. Do not retry.)
//
// R5 structure: 256x128 tiles, 512 threads (8 waves of 64x64 output), BK=128
// (4 rounds, ONE barrier per round). Rationale (R4 counters: MfmaUtil 29%,
// 43% stall): B-tile reuse doubles (8 waves share the staged tile) and each
// barrier now fences 64 MFMAs/wave instead of 32, so the round-top drain
// waits on DMAs issued a full round earlier. __launch_bounds__(512,4) caps
// regs at 128 -> 2 blocks/CU (16 waves, 68 KB LDS) for cross-block stall
// filling; A fragments therefore loaded inline per half (no ping-pong;
// acc 64 + af 16 + bf 16 + addr ~22 = ~118 regs).
//
// B LDS: 2 x [128 rows x 128 B]; phys 16B chunk = logical ^ (row&7), applied
// by permuting the DMA's GLOBAL source (LDS dest linear). b128 fragment
// reads: lanes with equal (quad, colid&7) pairs are 2-way on banks = free.
__global__ __launch_bounds__(512, 4) void sym_gemm_k(
    const unsigned char* __restrict__ Fa, const unsigned char* __restrict__ Fb,
    float* __restrict__ rowsum, float* __restrict__ pairsim) {
  // XCD-contiguous remap: each XCD (bx%8) gets a contiguous 132-block range
  int bx = blockIdx.x;
  int gbx = (bx & 7) * (NBLOCKS / 8) + (bx >> 3);
  // (rb, cb): 256-row block rb, 128-col block cb, cb >= 2*rb (upper triangle)
  int rb = 0, rem = gbx;
  while (rem >= 64 - 2 * rb) { rem -= 64 - 2 * rb; ++rb; }
  const int cb = 2 * rb + rem;
  const int row0 = rb * 256, col0 = cb * 128;

  const int tid = threadIdx.x;
  const int wave = tid >> 6;          // 0..7
  const int lane = tid & 63;
  const int quad = lane >> 4;
  const int colid = lane & 15;
  const int wr0 = (wave >> 1) * 64;   // wave's row offset within tile (0..192)
  const int wc0 = (wave & 1) * 64;    // wave's col offset within tile (0,64)

  __shared__ __align__(16) unsigned char Blds[2][128 * 128];
  __shared__ float redrow[256];
  __shared__ float redcol[128];

  if (tid < 256) redrow[tid] = 0.0f;
  if (tid < 128) redcol[tid] = 0.0f;

  // B staging: 16 x 1KB insts/round, wave w owns insts {w, w+8}.
  // Inst i covers rows [i*8, i*8+8): lane -> r = i*8 + (lane>>3),
  // phys chunk = lane&7, logical chunk = (lane&7) ^ (lane>>3)  [= phys ^ (r&7)]
  const unsigned char* srcB[2]; int dstO[2];
  {
    int rloc = lane >> 3;
    int l = (lane & 7) ^ rloc;
    #pragma unroll
    for (int seg = 0; seg < 2; ++seg) {
      int inst = wave + seg * 8;
      srcB[seg] = Fb + (size_t)(col0 + inst * 8 + rloc) * DIM + l * 16;
      dstO[seg] = inst * 1024;        // 8 rows x 128 B per inst, linear dest
    }
  }

  // A global fragment pointers: tile t -> panel (row0+wr0+t*16)>>4;
  // substep ss = kc*2+h, quad q -> chunk ss*4+q; colid -> row-in-panel.
  const unsigned char* agp[4];
  #pragma unroll
  for (int t = 0; t < 4; ++t)
    agp[t] = Fa + (size_t)((row0 + wr0 + t * 16) >> 4) * 8192 +
             quad * 256 + colid * 16;

  // B fragment LDS byte offsets (half h applied as XOR h<<6):
  // rc = wc0+u*16+colid; phys = (h*4+quad) ^ (rc&7); byte = rc*128 + phys*16.
  int bq[4];
  #pragma unroll
  for (int u = 0; u < 4; ++u) {
    int rc = wc0 + u * 16 + colid;
    bq[u] = rc * 128 + ((quad ^ (colid & 7)) << 4);
  }

  f32x4 acc[4][4];
  #pragma unroll
  for (int t = 0; t < 4; ++t)
    #pragma unroll
    for (int u = 0; u < 4; ++u) acc[t][u] = (f32x4){0.f, 0.f, 0.f, 0.f};

  // Prologue: stage round 0 into buf 0 (drained by the kc=0 loop-top barrier).
  #pragma unroll
  for (int seg = 0; seg < 2; ++seg)
    async16(srcB[seg], &Blds[0][0] + dstO[seg]);

  #pragma unroll
  for (int kc = 0; kc < 4; ++kc) {
    __syncthreads();   // drains DMA(kc) staged last round; prior reads done
    if (kc < 3) {
      #pragma unroll
      for (int seg = 0; seg < 2; ++seg)
        async16(srcB[seg] + (kc + 1) * 128, &Blds[(kc & 1) ^ 1][0] + dstO[seg]);
    }
    #pragma unroll
    for (int h = 0; h < 2; ++h) {
      const int ss = kc * 2 + h;
      long2v af[4];
      #pragma unroll
      for (int t = 0; t < 4; ++t)
        af[t] = *reinterpret_cast<const long2v*>(agp[t] + ss * 1024);
      long2v bf[4];
      #pragma unroll
      for (int u = 0; u < 4; ++u)
        bf[u] = *reinterpret_cast<const long2v*>(
            &Blds[kc & 1][0] + (bq[u] ^ (h << 6)));
      #pragma unroll
      for (int s = 0; s < 2; ++s)
        #pragma unroll
        for (int t = 0; t < 4; ++t)
          #pragma unroll
          for (int u = 0; u < 4; ++u)
            acc[t][u] = __builtin_amdgcn_mfma_f32_16x16x32_fp8_fp8(
                af[t][s], bf[u][s], acc[t][u], 0, 0, 0);
    }
  }

  // Epilogue. C/D layout: col = lane&15, row = quad*4 + reg (m89-verified).
  float re[4][4];
  float ce[4];
  #pragma unroll
  for (int t = 0; t < 4; ++t)
    #pragma unroll
    for (int r = 0; r < 4; ++r) re[t][r] = 0.0f;
  #pragma unroll
  for (int u = 0; u < 4; ++u) ce[u] = 0.0f;

  #pragma unroll
  for (int t = 0; t < 4; ++t) {
    #pragma unroll
    for (int u = 0; u < 4; ++u) {
      f32x4 a = acc[t][u];
      const int gc = col0 + wc0 + u * 16 + colid;
      #pragma unroll
      for (int r = 0; r < 4; ++r) {
        int grow = row0 + wr0 + t * 16 + quad * 4 + r;
        float sim = a[r] * INV_T;
        float e = (gc > grow) ? __expf(sim) : 0.0f;  // strict upper triangle
        re[t][r] += e;
        ce[u] += e;
        if (gc == grow + HALF_N && grow < HALF_N) {
          pairsim[grow] = sim;         // unique writer per pair
          pairsim[gc] = sim;
        }
      }
    }
  }

  // Row sums: reduce across the 16 col-lanes, LDS-accumulate.
  #pragma unroll
  for (int t = 0; t < 4; ++t)
    #pragma unroll
    for (int r = 0; r < 4; ++r) {
      float v = re[t][r];
      v += __shfl_xor(v, 1); v += __shfl_xor(v, 2);
      v += __shfl_xor(v, 4); v += __shfl_xor(v, 8);
      if (colid == 0) atomicAdd(&redrow[wr0 + t * 16 + quad * 4 + r], v);
    }
  // Col sums: reduce across the 4 quads (this wave's 64 rows).
  #pragma unroll
  for (int u = 0; u < 4; ++u) {
    float v = ce[u];
    v += __shfl_xor(v, 16); v += __shfl_xor(v, 32);
    if (lane < 16) atomicAdd(&redcol[wc0 + u * 16 + colid], v);
  }
  __syncthreads();
  if (tid < 256)      atomicAdd(&rowsum[row0 + tid], redrow[tid]);
  else if (tid < 384) atomicAdd(&rowsum[col0 + tid - 256], redcol[tid - 256]);
}

// Kernel 3: loss partials. 32 blocks x 256 threads, one row each;
// per-wave reduce then one atomicAdd per wave into out (zeroed in kernel 1).
__global__ __launch_bounds__(256) void finalize_k(
    const float* __restrict__ rowsum, const float* __restrict__ pairsim,
    float* __restrict__ out) {
  int i = blockIdx.x * 256 + threadIdx.x;
  float local = logf(rowsum[i]) - pairsim[i];
  #pragma unroll
  for (int off = 1; off < 64; off <<= 1) local += __shfl_xor(local, off);
  if ((threadIdx.x & 63) == 0)
    atomicAdd(out, local * (1.0f / (float)NROWS));
}

extern "C" void kernel_launch(void* const* d_in, const int* in_sizes, int n_in,
                              void* d_out, int out_size, void* d_ws, size_t ws_size,
                              hipStream_t stream) {
  const float* f1 = (const float*)d_in[0];
  const float* f2 = (const float*)d_in[1];
  unsigned char* Fa = (unsigned char*)d_ws;                     // 4 MB fp8
  unsigned char* Fb = Fa + (size_t)NROWS * DIM;                 // 4 MB fp8
  float* rowsum = (float*)(Fb + (size_t)NROWS * DIM);
  float* pairsim = rowsum + NROWS;
  float* out = (float*)d_out;

  norm_cast_k<<<NROWS / 4, 256, 0, stream>>>(f1, f2, Fa, Fb, rowsum, out);
  sym_gemm_k<<<NBLOCKS, 512, 0, stream>>>(Fa, Fb, rowsum, pairsim);
  finalize_k<<<NROWS / 256, 256, 0, stream>>>(rowsum, pairsim, out);
}